// Round 8
// baseline (1041.663 us; speedup 1.0000x reference)
//
#include <hip/hip_runtime.h>
#include <math.h>

#define NEG 0.2f
#define CSRB 256

typedef __attribute__((ext_vector_type(8))) short bf16x8;
typedef __attribute__((ext_vector_type(4))) float f32x4;
typedef unsigned int u32;

__device__ inline float bf2f(unsigned short u) {
    union { unsigned int i; float f; } v; v.i = ((unsigned int)u) << 16; return v.f;
}
__device__ inline unsigned short f2bf(float f) {
    union { float f; unsigned int i; } v; v.f = f;
    unsigned int r = v.i + 0x7FFF + ((v.i >> 16) & 1);
    return (unsigned short)(r >> 16);
}
__device__ inline void load_lds16(const unsigned short* g, unsigned short* l) {
    __builtin_amdgcn_global_load_lds((const __attribute__((address_space(1))) u32*)g,
                                     (__attribute__((address_space(3))) u32*)l, 16, 0, 0);
}

// software barrier over nb blocks (all co-resident via cooperative launch).
// release fence -> atomic arrive -> spin -> acquire fence.
__device__ inline void swbar(int* ctr, int nb, int& ph) {
    __syncthreads();
    if (threadIdx.x == 0) {
        __threadfence();
        __hip_atomic_fetch_add(ctr, 1, __ATOMIC_RELEASE, __HIP_MEMORY_SCOPE_AGENT);
        ph += nb;
        while (__hip_atomic_load(ctr, __ATOMIC_ACQUIRE, __HIP_MEMORY_SCOPE_AGENT) < ph)
            __builtin_amdgcn_s_sleep(2);
        __threadfence();
    }
    __syncthreads();
}

// inclusive Hillis-Steele scan over the 256-thread block; sh = 256 ints LDS
__device__ inline int blockscan(int v, int* sh) {
    int t = threadIdx.x;
    sh[t] = v; __syncthreads();
#pragma unroll
    for (int off = 1; off < 256; off <<= 1) {
        int u = (t >= off) ? sh[t - off] : 0;
        __syncthreads();
        v += u; sh[t] = v;
        __syncthreads();
    }
    return v;
}

// 128x64 split-bf16 GEMM tile + fused attention-score epilogue (r6 body)
__device__ inline void gemm_tile(const unsigned short* __restrict__ A,
                                 const unsigned short* __restrict__ BtBase,
                                 unsigned short* __restrict__ Cout,
                                 const float* __restrict__ avs, const float* __restrict__ avd,
                                 float* __restrict__ esv, float* __restrict__ edv,
                                 int n, int bm, unsigned short* As, unsigned short* Bs,
                                 int wave, int lane) {
    const int lm = lane & 15, kq = lane >> 4;
    const int rA = lane >> 2, cA = (lane & 3) * 8;
    f32x4 acc[2][4] = {};
    for (int k0 = 0; k0 < 768; k0 += 32) {
        const int ka = (k0 < 512) ? k0 : k0 - 512;
#pragma unroll
        for (int i = 0; i < 2; ++i) {
            int c = wave * 2 + i;
            int gr = bm + c * 16 + rA;
            if (gr >= n) gr = n - 1;  // clamp: discarded at store
            load_lds16(A + (size_t)gr * 512 + ka + cA, As + c * 16 * 32);
        }
        load_lds16(BtBase + (size_t)(wave * 16 + rA) * 768 + k0 + cA, Bs + wave * 16 * 32);
        __syncthreads();
        bf16x8 af[2], bfr[4];
#pragma unroll
        for (int f = 0; f < 2; ++f) af[f] = *(const bf16x8*)(As + (wave * 32 + f * 16 + lm) * 32 + kq * 8);
#pragma unroll
        for (int f = 0; f < 4; ++f) bfr[f] = *(const bf16x8*)(Bs + (f * 16 + lm) * 32 + kq * 8);
#pragma unroll
        for (int fr = 0; fr < 2; ++fr)
#pragma unroll
            for (int fc = 0; fc < 4; ++fc)
                acc[fr][fc] = __builtin_amdgcn_mfma_f32_16x16x32_bf16(af[fr], bfr[fc], acc[fr][fc], 0, 0, 0);
        __syncthreads();
    }
    float asv[4], adv[4];
#pragma unroll
    for (int fc = 0; fc < 4; ++fc) { asv[fc] = avs[fc * 16 + lm]; adv[fc] = avd[fc * 16 + lm]; }
    const int wm = wave * 32;
#pragma unroll
    for (int fr = 0; fr < 2; ++fr)
#pragma unroll
        for (int i = 0; i < 4; ++i) {
            int row = bm + wm + fr * 16 + kq * 4 + i;
            float se = 0.f, de = 0.f;
#pragma unroll
            for (int fc = 0; fc < 4; ++fc) {
                float cc = acc[fr][fc][i];
                se = fmaf(asv[fc], cc, se);
                de = fmaf(adv[fc], cc, de);
            }
#pragma unroll
            for (int off = 1; off < 16; off <<= 1) {
                se += __shfl_xor(se, off, 64);
                de += __shfl_xor(de, off, 64);
            }
            if (row < n) {
                if (lm == 0) { esv[row] = se; edv[row] = de; }
#pragma unroll
                for (int fc = 0; fc < 4; ++fc)
                    Cout[(size_t)row * 64 + fc * 16 + lm] = f2bf(acc[fr][fc][i]);
            }
        }
}

__global__ __launch_bounds__(256, 4) void mega(const float* __restrict__ x,
                                               const int* __restrict__ ei,
                                               const float* __restrict__ W1,
                                               const float* __restrict__ a1s,
                                               const float* __restrict__ a1d,
                                               const float* __restrict__ b1,
                                               const float* __restrict__ W2,
                                               const float* __restrict__ a2s,
                                               const float* __restrict__ a2d,
                                               const float* __restrict__ b2,
                                               float* __restrict__ out,
                                               char* __restrict__ ws, int n, int E) {
    __shared__ char smem[12544];
    unsigned short* As = (unsigned short*)smem;            // 8192 B
    unsigned short* Bs = (unsigned short*)(smem + 8192);   // 4096 B
    int* ssc = (int*)smem;                                 // scan scratch (aliased)

    const int EP = E + n;
    char* p = ws;
    auto take = [&](size_t b) { char* r = p; p += (b + 255) & ~(size_t)255; return r; };
    int* ctr    = (int*)take(256);   // [0]=global barrier, [1]=CSR subset (memset by host)
    int* deg    = (int*)take((size_t)n * 4);
    int* offs   = (int*)take((size_t)(n + 1) * 4);
    int* cursor = (int*)take((size_t)n * 4);
    int* csr    = (int*)take((size_t)EP * 4);
    unsigned short* hstk = (unsigned short*)take((size_t)n * 512 * 2);  // x' then h1a'
    unsigned short* Wt1  = (unsigned short*)take((size_t)256 * 768 * 2);
    unsigned short* Wt2  = (unsigned short*)take((size_t)64 * 768 * 2);
    unsigned short* h1   = (unsigned short*)take((size_t)n * 256 * 2);  // head-major [4][n][64]
    unsigned short* h2   = (unsigned short*)take((size_t)n * 64 * 2);
    float* es1 = (float*)take((size_t)n * 4 * 4);  // head-major [4][n]
    float* ed1 = (float*)take((size_t)n * 4 * 4);
    float* es2 = (float*)take((size_t)n * 4);
    float* ed2 = (float*)take((size_t)n * 4);
    int* bsum = (int*)take(256 * 4);
    int* bpre = (int*)take(256 * 4);

    const int bid = blockIdx.x, tid = threadIdx.x, G = gridDim.x;
    const int wave = tid >> 6, lane = tid & 63;
    int phg = 0, phc = 0;

    // ================= P0: conv (gemm blocks) || zero deg (CSR blocks) ========
    if (bid < CSRB) {
        for (int i = bid * 256 + tid; i < n; i += CSRB * 256) deg[i] = 0;
    } else {
        const int nt = (G - CSRB) * 256;
        const int idx0 = (bid - CSRB) * 256 + tid;
        for (int i = idx0; i < n * 64; i += nt) {  // conv_x -> [Ah|Al] stacked
            int e0 = i * 4, node = e0 >> 8, c = e0 & 255;
            float4 f = *(const float4*)(x + e0);
            unsigned short h0 = f2bf(f.x), hh1 = f2bf(f.y), h2v = f2bf(f.z), h3 = f2bf(f.w);
            uint2 hi, lo;
            hi.x = (u32)h0 | ((u32)hh1 << 16);
            hi.y = (u32)h2v | ((u32)h3 << 16);
            lo.x = (u32)f2bf(f.x - bf2f(h0)) | ((u32)f2bf(f.y - bf2f(hh1)) << 16);
            lo.y = (u32)f2bf(f.z - bf2f(h2v)) | ((u32)f2bf(f.w - bf2f(h3)) << 16);
            *(uint2*)(hstk + (size_t)node * 512 + c) = hi;
            *(uint2*)(hstk + (size_t)node * 512 + 256 + c) = lo;
        }
        for (int i2 = idx0; i2 < 245760; i2 += nt) {  // conv_w (both layers)
            int i = i2;
            const float* W; unsigned short* Wt; int outc;
            if (i < 196608) { W = W1; Wt = Wt1; outc = 256; }
            else            { i -= 196608; W = W2; Wt = Wt2; outc = 64; }
            int nn = i / 768, k = i % 768;
            int ksrc = (k < 256) ? k : (k < 512 ? k - 256 : k - 512);
            float f = W[(size_t)ksrc * outc + nn];
            unsigned short hh = f2bf(f);
            if (k >= 512) hh = f2bf(f - bf2f(hh));
            Wt[i] = hh;
        }
    }
    swbar(ctr, G, phg);  // global

    // ========== P1: CSR chain (blocks 0..255) || GEMM1+scores (rest) ==========
    if (bid < CSRB) {
        for (int e = bid * 256 + tid; e < EP; e += CSRB * 256) {
            int d = (e < E) ? ei[E + e] : (e - E);
            atomicAdd(&deg[d], 1);
        }
        swbar(ctr + 1, CSRB, phc);
        const int CH = (n + 255) >> 8;            // elems per CSR block (<=256)
        const int b0 = bid * CH;
        int cnt = n - b0; cnt = (cnt < 0) ? 0 : ((cnt > CH) ? CH : cnt);
        int v = (tid < cnt) ? deg[b0 + tid] : 0;
        int incl = blockscan(v, ssc);
        if (tid == 255) bsum[bid] = incl;         // block total
        swbar(ctr + 1, CSRB, phc);
        if (bid == 0) {                           // scan of block totals
            int bv = bsum[tid];
            int bi = blockscan(bv, ssc);
            bpre[tid] = bi - bv;                  // exclusive
            if (tid == 255) offs[n] = bi;
        }
        swbar(ctr + 1, CSRB, phc);
        int base = bpre[bid];
        int excl = base + incl - v;
        if (tid < cnt) { offs[b0 + tid] = excl; cursor[b0 + tid] = excl; }
        swbar(ctr + 1, CSRB, phc);
        for (int e = bid * 256 + tid; e < EP; e += CSRB * 256) {
            int s, d;
            if (e < E) { s = ei[e]; d = ei[E + e]; }
            else       { s = d = e - E; }
            int pos = atomicAdd(&cursor[d], 1);
            csr[pos] = s;
        }
    } else {
        const int RT = (n + 127) >> 7;
        for (int T = bid - CSRB; T < RT * 4; T += G - CSRB) {
            int tm = T >> 2, head = T & 3;
            gemm_tile(hstk, Wt1 + (size_t)head * 64 * 768, h1 + (size_t)head * n * 64,
                      a1s + head * 64, a1d + head * 64, es1 + (size_t)head * n,
                      ed1 + (size_t)head * n, n, tm * 128, As, Bs, wave, lane);
        }
    }
    swbar(ctr, G, phg);  // global

    // ================= P2: agg1 (two-phase, XCD-local head tables) ============
    {
        const int head = bid & 3;
        const int hb = bid >> 2;
        const int grp = lane >> 4, li = lane & 15, ch = li * 4;
        const unsigned short* ht = h1 + (size_t)head * n * 64;
        const float* esh = es1 + (size_t)head * n;
        const float* edh = ed1 + (size_t)head * n;
        for (int node = hb * 4 + wave; node < n; node += G) {
            const float edst = edh[node];
            const int j0 = offs[node], j1 = offs[node + 1];
            float z = 0.f;
            float a[4] = {};
            for (int base = j0; base < j1; base += 64) {
                int cnt = j1 - base; if (cnt > 64) cnt = 64;
                int idxl = base + lane;
                int sA = csr[idxl < j1 ? idxl : j0];
                float pA = 0.f;
                if (lane < cnt) {
                    float l = esh[sA] + edst;
                    l = (l > 0.f) ? l : NEG * l;
                    pA = __expf(l);
                }
                float zz = pA;
#pragma unroll
                for (int off = 1; off < 64; off <<= 1) zz += __shfl_xor(zz, off, 64);
                z += zz;
                for (int e = 0; e < cnt; e += 8) {
                    int i0 = e + grp, i1 = e + grp + 4;
                    int s0 = __shfl(sA, i0 & 63, 64);
                    int s1 = __shfl(sA, i1 & 63, 64);
                    float q0 = __shfl(pA, i0 & 63, 64);
                    float q1 = __shfl(pA, i1 & 63, 64);
                    float p0 = (i0 < cnt) ? q0 : 0.f;
                    float p1 = (i1 < cnt) ? q1 : 0.f;
                    uint2 w0 = *(const uint2*)(ht + (size_t)s0 * 64 + ch);
                    uint2 w1 = *(const uint2*)(ht + (size_t)s1 * 64 + ch);
                    a[0] = fmaf(p0, bf2f((unsigned short)(w0.x & 0xffffu)), a[0]);
                    a[1] = fmaf(p0, bf2f((unsigned short)(w0.x >> 16)), a[1]);
                    a[2] = fmaf(p0, bf2f((unsigned short)(w0.y & 0xffffu)), a[2]);
                    a[3] = fmaf(p0, bf2f((unsigned short)(w0.y >> 16)), a[3]);
                    a[0] = fmaf(p1, bf2f((unsigned short)(w1.x & 0xffffu)), a[0]);
                    a[1] = fmaf(p1, bf2f((unsigned short)(w1.x >> 16)), a[1]);
                    a[2] = fmaf(p1, bf2f((unsigned short)(w1.y & 0xffffu)), a[2]);
                    a[3] = fmaf(p1, bf2f((unsigned short)(w1.y >> 16)), a[3]);
                }
            }
#pragma unroll
            for (int off = 16; off < 64; off <<= 1)
#pragma unroll
                for (int c = 0; c < 4; ++c) a[c] += __shfl_xor(a[c], off, 64);
            if (grp == 0) {
                float inv = 1.f / z;
                float r[4]; unsigned short qh[4];
#pragma unroll
                for (int c = 0; c < 4; ++c) {
                    r[c] = a[c] * inv + b1[head * 64 + ch + c];
                    r[c] = (r[c] > 0.f) ? r[c] : (__expf(r[c]) - 1.f);  // ELU
                    qh[c] = f2bf(r[c]);
                }
                uint2 hiw, low;
                hiw.x = (u32)qh[0] | ((u32)qh[1] << 16);
                hiw.y = (u32)qh[2] | ((u32)qh[3] << 16);
                low.x = (u32)f2bf(r[0] - bf2f(qh[0])) | ((u32)f2bf(r[1] - bf2f(qh[1])) << 16);
                low.y = (u32)f2bf(r[2] - bf2f(qh[2])) | ((u32)f2bf(r[3] - bf2f(qh[3])) << 16);
                *(uint2*)(hstk + (size_t)node * 512 + head * 64 + ch) = hiw;
                *(uint2*)(hstk + (size_t)node * 512 + 256 + head * 64 + ch) = low;
            }
        }
    }
    swbar(ctr, G, phg);  // global

    // ================= P3: GEMM2 + scores2 ====================================
    {
        const int RT = (n + 127) >> 7;
        for (int T = bid; T < RT; T += G)
            gemm_tile(hstk, Wt2, h2, a2s, a2d, es2, ed2, n, T * 128, As, Bs, wave, lane);
    }
    swbar(ctr, G, phg);  // global

    // ================= P4: agg2 -> out ========================================
    {
        const int grp = lane >> 4, li = lane & 15, ch = li * 4;
        for (int node = bid * 4 + wave; node < n; node += G * 4) {
            const float edst = ed2[node];
            const int j0 = offs[node], j1 = offs[node + 1];
            float z = 0.f;
            float a[4] = {};
            for (int base = j0; base < j1; base += 64) {
                int cnt = j1 - base; if (cnt > 64) cnt = 64;
                int idxl = base + lane;
                int sA = csr[idxl < j1 ? idxl : j0];
                float pA = 0.f;
                if (lane < cnt) {
                    float l = es2[sA] + edst;
                    l = (l > 0.f) ? l : NEG * l;
                    pA = __expf(l);
                }
                float zz = pA;
#pragma unroll
                for (int off = 1; off < 64; off <<= 1) zz += __shfl_xor(zz, off, 64);
                z += zz;
                for (int e = 0; e < cnt; e += 8) {
                    int i0 = e + grp, i1 = e + grp + 4;
                    int s0 = __shfl(sA, i0 & 63, 64);
                    int s1 = __shfl(sA, i1 & 63, 64);
                    float q0 = __shfl(pA, i0 & 63, 64);
                    float q1 = __shfl(pA, i1 & 63, 64);
                    float p0 = (i0 < cnt) ? q0 : 0.f;
                    float p1 = (i1 < cnt) ? q1 : 0.f;
                    uint2 w0 = *(const uint2*)(h2 + (size_t)s0 * 64 + ch);
                    uint2 w1 = *(const uint2*)(h2 + (size_t)s1 * 64 + ch);
                    a[0] = fmaf(p0, bf2f((unsigned short)(w0.x & 0xffffu)), a[0]);
                    a[1] = fmaf(p0, bf2f((unsigned short)(w0.x >> 16)), a[1]);
                    a[2] = fmaf(p0, bf2f((unsigned short)(w0.y & 0xffffu)), a[2]);
                    a[3] = fmaf(p0, bf2f((unsigned short)(w0.y >> 16)), a[3]);
                    a[0] = fmaf(p1, bf2f((unsigned short)(w1.x & 0xffffu)), a[0]);
                    a[1] = fmaf(p1, bf2f((unsigned short)(w1.x >> 16)), a[1]);
                    a[2] = fmaf(p1, bf2f((unsigned short)(w1.y & 0xffffu)), a[2]);
                    a[3] = fmaf(p1, bf2f((unsigned short)(w1.y >> 16)), a[3]);
                }
            }
#pragma unroll
            for (int off = 16; off < 64; off <<= 1)
#pragma unroll
                for (int c = 0; c < 4; ++c) a[c] += __shfl_xor(a[c], off, 64);
            if (grp == 0) {
                float inv = 1.f / z;
                float4 r;
                r.x = a[0] * inv + b2[ch + 0];
                r.y = a[1] * inv + b2[ch + 1];
                r.z = a[2] * inv + b2[ch + 2];
                r.w = a[3] * inv + b2[ch + 3];
                *(float4*)(out + (size_t)node * 64 + ch) = r;
            }
        }
    }
}

// ============ launch ============
extern "C" void kernel_launch(void* const* d_in, const int* in_sizes, int n_in,
                              void* d_out, int out_size, void* d_ws, size_t ws_size,
                              hipStream_t stream) {
    const float* x   = (const float*)d_in[0];
    const int*   ei  = (const int*)d_in[1];
    const float* W1  = (const float*)d_in[2];
    const float* a1s = (const float*)d_in[3];
    const float* a1d = (const float*)d_in[4];
    const float* b1  = (const float*)d_in[5];
    const float* W2  = (const float*)d_in[6];
    const float* a2s = (const float*)d_in[7];
    const float* a2d = (const float*)d_in[8];
    const float* b2  = (const float*)d_in[9];
    float* out = (float*)d_out;
    char* ws = (char*)d_ws;

    int N = in_sizes[0] / 256;   // 20000
    int E = in_sizes[1] / 2;     // 320000

    // zero the two barrier counters (ws is re-poisoned 0xAA before every launch)
    hipMemsetAsync(d_ws, 0, 8, stream);

    int nb = 0;
    hipOccupancyMaxActiveBlocksPerMultiprocessor(&nb, mega, 256, 0);
    if (nb < 2) nb = 2;          // launch_bounds(256,4) should give >=4
    int G = nb * 256;
    if (G > 1024) G = 1024;      // 4 blocks/CU target

    void* args[] = { (void*)&x, (void*)&ei, (void*)&W1, (void*)&a1s, (void*)&a1d,
                     (void*)&b1, (void*)&W2, (void*)&a2s, (void*)&a2d, (void*)&b2,
                     (void*)&out, (void*)&ws, (void*)&N, (void*)&E };
    hipLaunchCooperativeKernel(mega, dim3(G), dim3(256), args, 0, stream);
}

// Round 9
// 605.666 us; speedup vs baseline: 1.7199x; 1.7199x over previous
//
#include <hip/hip_runtime.h>
#include <math.h>

#define NEG 0.2f
#define CSRB 256

typedef __attribute__((ext_vector_type(8))) short bf16x8;
typedef __attribute__((ext_vector_type(4))) float f32x4;
typedef unsigned int u32;

__device__ inline float bf2f(unsigned short u) {
    union { unsigned int i; float f; } v; v.i = ((unsigned int)u) << 16; return v.f;
}
__device__ inline unsigned short f2bf(float f) {
    union { float f; unsigned int i; } v; v.f = f;
    unsigned int r = v.i + 0x7FFF + ((v.i >> 16) & 1);
    return (unsigned short)(r >> 16);
}
__device__ inline void load_lds16(const unsigned short* g, unsigned short* l) {
    __builtin_amdgcn_global_load_lds((const __attribute__((address_space(1))) u32*)g,
                                     (__attribute__((address_space(3))) u32*)l, 16, 0, 0);
}

// software barrier over nb blocks (co-resident, cooperative launch).
// CRITICAL: poll with RELAXED loads (no buffer_inv per poll); fence ONCE on
// each side. r8's acquire-polling invalidated the XCD L2s continuously and
// collapsed the whole kernel to latency-bound 185 GB/s.
__device__ inline void swbar(int* ctr, int nb, int& ph) {
    __syncthreads();
    if (threadIdx.x == 0) {
        __threadfence();  // release: flush our writes to coherence point
        __hip_atomic_fetch_add(ctr, 1, __ATOMIC_RELAXED, __HIP_MEMORY_SCOPE_AGENT);
        ph += nb;
        while (__hip_atomic_load(ctr, __ATOMIC_RELAXED, __HIP_MEMORY_SCOPE_AGENT) < ph)
            __builtin_amdgcn_s_sleep(8);
        __threadfence();  // acquire: single L2 inv now that all arrived
    }
    __syncthreads();
}

// inclusive Hillis-Steele scan over the 256-thread block; sh = 256 ints LDS
__device__ inline int blockscan(int v, int* sh) {
    int t = threadIdx.x;
    sh[t] = v; __syncthreads();
#pragma unroll
    for (int off = 1; off < 256; off <<= 1) {
        int u = (t >= off) ? sh[t - off] : 0;
        __syncthreads();
        v += u; sh[t] = v;
        __syncthreads();
    }
    return v;
}

// 128x64 split-bf16 GEMM tile + fused attention-score epilogue
__device__ inline void gemm_tile(const unsigned short* __restrict__ A,
                                 const unsigned short* __restrict__ BtBase,
                                 unsigned short* __restrict__ Cout,
                                 const float* __restrict__ avs, const float* __restrict__ avd,
                                 float* __restrict__ esv, float* __restrict__ edv,
                                 int n, int bm, unsigned short* As, unsigned short* Bs,
                                 int wave, int lane) {
    const int lm = lane & 15, kq = lane >> 4;
    const int rA = lane >> 2, cA = (lane & 3) * 8;
    f32x4 acc[2][4] = {};
    for (int k0 = 0; k0 < 768; k0 += 32) {
        const int ka = (k0 < 512) ? k0 : k0 - 512;
#pragma unroll
        for (int i = 0; i < 2; ++i) {
            int c = wave * 2 + i;
            int gr = bm + c * 16 + rA;
            if (gr >= n) gr = n - 1;  // clamp: discarded at store
            load_lds16(A + (size_t)gr * 512 + ka + cA, As + c * 16 * 32);
        }
        load_lds16(BtBase + (size_t)(wave * 16 + rA) * 768 + k0 + cA, Bs + wave * 16 * 32);
        __syncthreads();
        bf16x8 af[2], bfr[4];
#pragma unroll
        for (int f = 0; f < 2; ++f) af[f] = *(const bf16x8*)(As + (wave * 32 + f * 16 + lm) * 32 + kq * 8);
#pragma unroll
        for (int f = 0; f < 4; ++f) bfr[f] = *(const bf16x8*)(Bs + (f * 16 + lm) * 32 + kq * 8);
#pragma unroll
        for (int fr = 0; fr < 2; ++fr)
#pragma unroll
            for (int fc = 0; fc < 4; ++fc)
                acc[fr][fc] = __builtin_amdgcn_mfma_f32_16x16x32_bf16(af[fr], bfr[fc], acc[fr][fc], 0, 0, 0);
        __syncthreads();
    }
    float asv[4], adv[4];
#pragma unroll
    for (int fc = 0; fc < 4; ++fc) { asv[fc] = avs[fc * 16 + lm]; adv[fc] = avd[fc * 16 + lm]; }
    const int wm = wave * 32;
#pragma unroll
    for (int fr = 0; fr < 2; ++fr)
#pragma unroll
        for (int i = 0; i < 4; ++i) {
            int row = bm + wm + fr * 16 + kq * 4 + i;
            float se = 0.f, de = 0.f;
#pragma unroll
            for (int fc = 0; fc < 4; ++fc) {
                float cc = acc[fr][fc][i];
                se = fmaf(asv[fc], cc, se);
                de = fmaf(adv[fc], cc, de);
            }
#pragma unroll
            for (int off = 1; off < 16; off <<= 1) {
                se += __shfl_xor(se, off, 64);
                de += __shfl_xor(de, off, 64);
            }
            if (row < n) {
                if (lm == 0) { esv[row] = se; edv[row] = de; }
#pragma unroll
                for (int fc = 0; fc < 4; ++fc)
                    Cout[(size_t)row * 64 + fc * 16 + lm] = f2bf(acc[fr][fc][i]);
            }
        }
}

__global__ __launch_bounds__(256, 4) void mega(const float* __restrict__ x,
                                               const int* __restrict__ ei,
                                               const float* __restrict__ W1,
                                               const float* __restrict__ a1s,
                                               const float* __restrict__ a1d,
                                               const float* __restrict__ b1,
                                               const float* __restrict__ W2,
                                               const float* __restrict__ a2s,
                                               const float* __restrict__ a2d,
                                               const float* __restrict__ b2,
                                               float* __restrict__ out,
                                               char* __restrict__ ws, int n, int E) {
    __shared__ char smem[12544];
    unsigned short* As = (unsigned short*)smem;            // 8192 B
    unsigned short* Bs = (unsigned short*)(smem + 8192);   // 4096 B
    int* ssc = (int*)smem;                                 // scan scratch (aliased)

    const int EP = E + n;
    char* p = ws;
    auto take = [&](size_t b) { char* r = p; p += (b + 255) & ~(size_t)255; return r; };
    int* ctr    = (int*)take(256);   // [0]=global barrier, [1]=CSR subset (memset by host)
    int* deg    = (int*)take((size_t)n * 4);
    int* offs   = (int*)take((size_t)(n + 1) * 4);
    int* cursor = (int*)take((size_t)n * 4);
    int* csr    = (int*)take((size_t)EP * 4);
    unsigned short* hstk = (unsigned short*)take((size_t)n * 512 * 2);  // x' then h1a'
    unsigned short* Wt1  = (unsigned short*)take((size_t)256 * 768 * 2);
    unsigned short* Wt2  = (unsigned short*)take((size_t)64 * 768 * 2);
    unsigned short* h1   = (unsigned short*)take((size_t)n * 256 * 2);  // head-major [4][n][64]
    unsigned short* h2   = (unsigned short*)take((size_t)n * 64 * 2);
    float* es1 = (float*)take((size_t)n * 4 * 4);  // head-major [4][n]
    float* ed1 = (float*)take((size_t)n * 4 * 4);
    float* es2 = (float*)take((size_t)n * 4);
    float* ed2 = (float*)take((size_t)n * 4);
    int* bsum = (int*)take(256 * 4);
    int* bpre = (int*)take(256 * 4);

    const int bid = blockIdx.x, tid = threadIdx.x, G = gridDim.x;
    const int wave = tid >> 6, lane = tid & 63;
    int phg = 0, phc = 0;

    // ================= P0: conv (gemm blocks) || zero deg (CSR blocks) ========
    if (bid < CSRB) {
        for (int i = bid * 256 + tid; i < n; i += CSRB * 256) deg[i] = 0;
    } else {
        const int nt = (G - CSRB) * 256;
        const int idx0 = (bid - CSRB) * 256 + tid;
        for (int i = idx0; i < n * 64; i += nt) {  // conv_x -> [Ah|Al] stacked
            int e0 = i * 4, node = e0 >> 8, c = e0 & 255;
            float4 f = *(const float4*)(x + e0);
            unsigned short h0 = f2bf(f.x), hh1 = f2bf(f.y), h2v = f2bf(f.z), h3 = f2bf(f.w);
            uint2 hi, lo;
            hi.x = (u32)h0 | ((u32)hh1 << 16);
            hi.y = (u32)h2v | ((u32)h3 << 16);
            lo.x = (u32)f2bf(f.x - bf2f(h0)) | ((u32)f2bf(f.y - bf2f(hh1)) << 16);
            lo.y = (u32)f2bf(f.z - bf2f(h2v)) | ((u32)f2bf(f.w - bf2f(h3)) << 16);
            *(uint2*)(hstk + (size_t)node * 512 + c) = hi;
            *(uint2*)(hstk + (size_t)node * 512 + 256 + c) = lo;
        }
        for (int i2 = idx0; i2 < 245760; i2 += nt) {  // conv_w (both layers)
            int i = i2;
            const float* W; unsigned short* Wt; int outc;
            if (i < 196608) { W = W1; Wt = Wt1; outc = 256; }
            else            { i -= 196608; W = W2; Wt = Wt2; outc = 64; }
            int nn = i / 768, k = i % 768;
            int ksrc = (k < 256) ? k : (k < 512 ? k - 256 : k - 512);
            float f = W[(size_t)ksrc * outc + nn];
            unsigned short hh = f2bf(f);
            if (k >= 512) hh = f2bf(f - bf2f(hh));
            Wt[i] = hh;
        }
    }
    swbar(ctr, G, phg);  // global

    // ========== P1: CSR chain (blocks 0..255) || GEMM1+scores (rest) ==========
    if (bid < CSRB) {
        for (int e = bid * 256 + tid; e < EP; e += CSRB * 256) {
            int d = (e < E) ? ei[E + e] : (e - E);
            atomicAdd(&deg[d], 1);
        }
        swbar(ctr + 1, CSRB, phc);
        const int CH = (n + 255) >> 8;            // elems per CSR block (<=256)
        const int b0 = bid * CH;
        int cnt = n - b0; cnt = (cnt < 0) ? 0 : ((cnt > CH) ? CH : cnt);
        int v = (tid < cnt) ? deg[b0 + tid] : 0;
        int incl = blockscan(v, ssc);
        if (tid == 255) bsum[bid] = incl;         // block total
        swbar(ctr + 1, CSRB, phc);
        if (bid == 0) {                           // scan of block totals
            int bv = bsum[tid];
            int bi = blockscan(bv, ssc);
            bpre[tid] = bi - bv;                  // exclusive
            if (tid == 255) offs[n] = bi;
        }
        swbar(ctr + 1, CSRB, phc);
        int base = bpre[bid];
        int excl = base + incl - v;
        if (tid < cnt) { offs[b0 + tid] = excl; cursor[b0 + tid] = excl; }
        swbar(ctr + 1, CSRB, phc);
        for (int e = bid * 256 + tid; e < EP; e += CSRB * 256) {
            int s, d;
            if (e < E) { s = ei[e]; d = ei[E + e]; }
            else       { s = d = e - E; }
            int pos = atomicAdd(&cursor[d], 1);
            csr[pos] = s;
        }
    } else {
        const int RT = (n + 127) >> 7;
        for (int T = bid - CSRB; T < RT * 4; T += G - CSRB) {
            int tm = T >> 2, head = T & 3;
            gemm_tile(hstk, Wt1 + (size_t)head * 64 * 768, h1 + (size_t)head * n * 64,
                      a1s + head * 64, a1d + head * 64, es1 + (size_t)head * n,
                      ed1 + (size_t)head * n, n, tm * 128, As, Bs, wave, lane);
        }
    }
    swbar(ctr, G, phg);  // global

    // ================= P2: agg1 (two-phase, XCD-local head tables) ============
    {
        const int head = bid & 3;
        const int hb = bid >> 2;
        const int grp = lane >> 4, li = lane & 15, ch = li * 4;
        const unsigned short* ht = h1 + (size_t)head * n * 64;
        const float* esh = es1 + (size_t)head * n;
        const float* edh = ed1 + (size_t)head * n;
        for (int node = hb * 4 + wave; node < n; node += G) {
            const float edst = edh[node];
            const int j0 = offs[node], j1 = offs[node + 1];
            float z = 0.f;
            float a[4] = {};
            for (int base = j0; base < j1; base += 64) {
                int cnt = j1 - base; if (cnt > 64) cnt = 64;
                int idxl = base + lane;
                int sA = csr[idxl < j1 ? idxl : j0];
                float pA = 0.f;
                if (lane < cnt) {
                    float l = esh[sA] + edst;
                    l = (l > 0.f) ? l : NEG * l;
                    pA = __expf(l);
                }
                float zz = pA;
#pragma unroll
                for (int off = 1; off < 64; off <<= 1) zz += __shfl_xor(zz, off, 64);
                z += zz;
                for (int e = 0; e < cnt; e += 8) {
                    int i0 = e + grp, i1 = e + grp + 4;
                    int s0 = __shfl(sA, i0 & 63, 64);
                    int s1 = __shfl(sA, i1 & 63, 64);
                    float q0 = __shfl(pA, i0 & 63, 64);
                    float q1 = __shfl(pA, i1 & 63, 64);
                    float p0 = (i0 < cnt) ? q0 : 0.f;
                    float p1 = (i1 < cnt) ? q1 : 0.f;
                    uint2 w0 = *(const uint2*)(ht + (size_t)s0 * 64 + ch);
                    uint2 w1 = *(const uint2*)(ht + (size_t)s1 * 64 + ch);
                    a[0] = fmaf(p0, bf2f((unsigned short)(w0.x & 0xffffu)), a[0]);
                    a[1] = fmaf(p0, bf2f((unsigned short)(w0.x >> 16)), a[1]);
                    a[2] = fmaf(p0, bf2f((unsigned short)(w0.y & 0xffffu)), a[2]);
                    a[3] = fmaf(p0, bf2f((unsigned short)(w0.y >> 16)), a[3]);
                    a[0] = fmaf(p1, bf2f((unsigned short)(w1.x & 0xffffu)), a[0]);
                    a[1] = fmaf(p1, bf2f((unsigned short)(w1.x >> 16)), a[1]);
                    a[2] = fmaf(p1, bf2f((unsigned short)(w1.y & 0xffffu)), a[2]);
                    a[3] = fmaf(p1, bf2f((unsigned short)(w1.y >> 16)), a[3]);
                }
            }
#pragma unroll
            for (int off = 16; off < 64; off <<= 1)
#pragma unroll
                for (int c = 0; c < 4; ++c) a[c] += __shfl_xor(a[c], off, 64);
            if (grp == 0) {
                float inv = 1.f / z;
                float r[4]; unsigned short qh[4];
#pragma unroll
                for (int c = 0; c < 4; ++c) {
                    r[c] = a[c] * inv + b1[head * 64 + ch + c];
                    r[c] = (r[c] > 0.f) ? r[c] : (__expf(r[c]) - 1.f);  // ELU
                    qh[c] = f2bf(r[c]);
                }
                uint2 hiw, low;
                hiw.x = (u32)qh[0] | ((u32)qh[1] << 16);
                hiw.y = (u32)qh[2] | ((u32)qh[3] << 16);
                low.x = (u32)f2bf(r[0] - bf2f(qh[0])) | ((u32)f2bf(r[1] - bf2f(qh[1])) << 16);
                low.y = (u32)f2bf(r[2] - bf2f(qh[2])) | ((u32)f2bf(r[3] - bf2f(qh[3])) << 16);
                *(uint2*)(hstk + (size_t)node * 512 + head * 64 + ch) = hiw;
                *(uint2*)(hstk + (size_t)node * 512 + 256 + head * 64 + ch) = low;
            }
        }
    }
    swbar(ctr, G, phg);  // global

    // ================= P3: GEMM2 + scores2 ====================================
    {
        const int RT = (n + 127) >> 7;
        for (int T = bid; T < RT; T += G)
            gemm_tile(hstk, Wt2, h2, a2s, a2d, es2, ed2, n, T * 128, As, Bs, wave, lane);
    }
    swbar(ctr, G, phg);  // global

    // ================= P4: agg2 -> out ========================================
    {
        const int grp = lane >> 4, li = lane & 15, ch = li * 4;
        for (int node = bid * 4 + wave; node < n; node += G * 4) {
            const float edst = ed2[node];
            const int j0 = offs[node], j1 = offs[node + 1];
            float z = 0.f;
            float a[4] = {};
            for (int base = j0; base < j1; base += 64) {
                int cnt = j1 - base; if (cnt > 64) cnt = 64;
                int idxl = base + lane;
                int sA = csr[idxl < j1 ? idxl : j0];
                float pA = 0.f;
                if (lane < cnt) {
                    float l = es2[sA] + edst;
                    l = (l > 0.f) ? l : NEG * l;
                    pA = __expf(l);
                }
                float zz = pA;
#pragma unroll
                for (int off = 1; off < 64; off <<= 1) zz += __shfl_xor(zz, off, 64);
                z += zz;
                for (int e = 0; e < cnt; e += 8) {
                    int i0 = e + grp, i1 = e + grp + 4;
                    int s0 = __shfl(sA, i0 & 63, 64);
                    int s1 = __shfl(sA, i1 & 63, 64);
                    float q0 = __shfl(pA, i0 & 63, 64);
                    float q1 = __shfl(pA, i1 & 63, 64);
                    float p0 = (i0 < cnt) ? q0 : 0.f;
                    float p1 = (i1 < cnt) ? q1 : 0.f;
                    uint2 w0 = *(const uint2*)(h2 + (size_t)s0 * 64 + ch);
                    uint2 w1 = *(const uint2*)(h2 + (size_t)s1 * 64 + ch);
                    a[0] = fmaf(p0, bf2f((unsigned short)(w0.x & 0xffffu)), a[0]);
                    a[1] = fmaf(p0, bf2f((unsigned short)(w0.x >> 16)), a[1]);
                    a[2] = fmaf(p0, bf2f((unsigned short)(w0.y & 0xffffu)), a[2]);
                    a[3] = fmaf(p0, bf2f((unsigned short)(w0.y >> 16)), a[3]);
                    a[0] = fmaf(p1, bf2f((unsigned short)(w1.x & 0xffffu)), a[0]);
                    a[1] = fmaf(p1, bf2f((unsigned short)(w1.x >> 16)), a[1]);
                    a[2] = fmaf(p1, bf2f((unsigned short)(w1.y & 0xffffu)), a[2]);
                    a[3] = fmaf(p1, bf2f((unsigned short)(w1.y >> 16)), a[3]);
                }
            }
#pragma unroll
            for (int off = 16; off < 64; off <<= 1)
#pragma unroll
                for (int c = 0; c < 4; ++c) a[c] += __shfl_xor(a[c], off, 64);
            if (grp == 0) {
                float inv = 1.f / z;
                float4 r;
                r.x = a[0] * inv + b2[ch + 0];
                r.y = a[1] * inv + b2[ch + 1];
                r.z = a[2] * inv + b2[ch + 2];
                r.w = a[3] * inv + b2[ch + 3];
                *(float4*)(out + (size_t)node * 64 + ch) = r;
            }
        }
    }
}

// ============ launch ============
extern "C" void kernel_launch(void* const* d_in, const int* in_sizes, int n_in,
                              void* d_out, int out_size, void* d_ws, size_t ws_size,
                              hipStream_t stream) {
    const float* x   = (const float*)d_in[0];
    const int*   ei  = (const int*)d_in[1];
    const float* W1  = (const float*)d_in[2];
    const float* a1s = (const float*)d_in[3];
    const float* a1d = (const float*)d_in[4];
    const float* b1  = (const float*)d_in[5];
    const float* W2  = (const float*)d_in[6];
    const float* a2s = (const float*)d_in[7];
    const float* a2d = (const float*)d_in[8];
    const float* b2  = (const float*)d_in[9];
    float* out = (float*)d_out;
    char* ws = (char*)d_ws;

    int N = in_sizes[0] / 256;   // 20000
    int E = in_sizes[1] / 2;     // 320000

    // zero the two barrier counters (ws is re-poisoned 0xAA before every launch)
    hipMemsetAsync(d_ws, 0, 8, stream);

    int nb = 0;
    hipOccupancyMaxActiveBlocksPerMultiprocessor(&nb, mega, 256, 0);
    if (nb < 2) nb = 2;
    int G = nb * 256;
    if (G > 1024) G = 1024;      // 4 blocks/CU target, all co-resident

    void* args[] = { (void*)&x, (void*)&ei, (void*)&W1, (void*)&a1s, (void*)&a1d,
                     (void*)&b1, (void*)&W2, (void*)&a2s, (void*)&a2d, (void*)&b2,
                     (void*)&out, (void*)&ws, (void*)&N, (void*)&E };
    hipLaunchCooperativeKernel(mega, dim3(G), dim3(256), args, 0, stream);
}